// Round 5
// baseline (3573.785 us; speedup 1.0000x reference)
//
#include <hip/hip_runtime.h>

// Problem constants: T=8, B=16, C_in=C_out=256, M=1024
#define TT 8
#define BB 16
#define CC 256
#define MM 1024

// ---------------------------------------------------------------------------
// Exact emulation of numpy float32 semantics:
//  - einsum('oc,tbcm->tbom'): per element, sequential ascending-c chain,
//    each step fl32(acc + fl32(w*x))  (separate mul/add roundings, no FMA)
//  - mean/var reductions: numpy pairwise_sum per 1024-row (8-accumulator
//    128-blocks + balanced combine), fp32 sequential carry over (t,b) slabs
//  - BN: d = fl(y - mean); yn = fl(d * rs); rs = fl(1/fl(sqrt(fl(var+1e-5))))
//    gamma=1, beta=0 applied with correctly-rounded ops (exact no-ops here)
//  - LIF: v = fl(v + fl(fl(yn - v) * 0.5)); s = (v >= 1); hard reset
// ---------------------------------------------------------------------------

// Compute one element-group (4 consecutive m) of y[t,b,o,:] with the
// np.einsum fp32 axpy semantics.
__device__ __forceinline__ void e1_row4(
    const float* __restrict__ x, const float* __restrict__ W,
    int t, int b, int o, int m0,
    float& y0, float& y1, float& y2, float& y3)
{
    const float* xs = x + ((size_t)(t * BB + b) * CC) * MM + m0;
    const float* wr = W + (size_t)o * CC;
    y0 = 0.0f; y1 = 0.0f; y2 = 0.0f; y3 = 0.0f;
    for (int c = 0; c < CC; ++c) {
        const float wc = wr[c];                       // wave-uniform -> s_load
        const float4 xv = *(const float4*)(xs + (size_t)c * MM);
        y0 = __fadd_rn(y0, __fmul_rn(wc, xv.x));
        y1 = __fadd_rn(y1, __fmul_rn(wc, xv.y));
        y2 = __fadd_rn(y2, __fmul_rn(wc, xv.z));
        y3 = __fadd_rn(y3, __fmul_rn(wc, xv.w));
    }
}

// numpy pairwise_sum over a contiguous 1024-float row (in LDS), exact.
// 1024 -> 2x512 -> 4x256 -> 8x128-blocks; each 128-block: 8 accumulators,
// 16 sequential terms each, combined ((r0+r1)+(r2+r3))+((r4+r5)+(r6+r7));
// blocks combined ((B0+B1)+(B2+B3))+((B4+B5)+(B6+B7)).
// Requires 256 threads; scratch >= 65 floats.
__device__ __forceinline__ float np_pairwise_1024(
    const float* __restrict__ yrow, float* __restrict__ scratch, int tid)
{
    if (tid < 64) {
        const int blk = tid >> 3;       // 128-elem base block
        const int k   = tid & 7;        // accumulator lane
        const float* p = yrow + blk * 128 + k;
        float r = p[0];
#pragma unroll
        for (int i = 1; i < 16; ++i) r = __fadd_rn(r, p[8 * i]);
        scratch[tid] = r;
    }
    __syncthreads();
    if (tid == 0) {
        float B[8];
#pragma unroll
        for (int blk = 0; blk < 8; ++blk) {
            const float* r = scratch + blk * 8;
            const float s01 = __fadd_rn(r[0], r[1]);
            const float s23 = __fadd_rn(r[2], r[3]);
            const float s45 = __fadd_rn(r[4], r[5]);
            const float s67 = __fadd_rn(r[6], r[7]);
            B[blk] = __fadd_rn(__fadd_rn(s01, s23), __fadd_rn(s45, s67));
        }
        const float c0 = __fadd_rn(B[0], B[1]);
        const float c1 = __fadd_rn(B[2], B[3]);
        const float c2 = __fadd_rn(B[4], B[5]);
        const float c3 = __fadd_rn(B[6], B[7]);
        scratch[64] = __fadd_rn(__fadd_rn(c0, c1), __fadd_rn(c2, c3));
    }
    __syncthreads();
    return scratch[64];
}

// ---------------------------------------------------------------------------
// Pass A: per-(t,b,o) row pairwise partial sums of y.
// grid: (o=256, tb=128), 256 threads.
// ---------------------------------------------------------------------------
__global__ __launch_bounds__(256) void pass_mean(
    const float* __restrict__ x, const float* __restrict__ W,
    float* __restrict__ part)
{
    __shared__ float yrow[1024];
    __shared__ float scratch[65];
    const int tid = threadIdx.x;
    const int o  = blockIdx.x;
    const int tb = blockIdx.y;
    const int t = tb >> 4, b = tb & 15;
    const int m0 = tid * 4;

    float y0, y1, y2, y3;
    e1_row4(x, W, t, b, o, m0, y0, y1, y2, y3);
    *(float4*)&yrow[m0] = make_float4(y0, y1, y2, y3);
    __syncthreads();
    const float P = np_pairwise_1024(yrow, scratch, tid);
    if (tid == 0) part[(size_t)tb * 256 + o] = P;
}

// sequential fp32 carry over the 128 (t,b) slabs in memory order, then /2^17
__global__ void reduce_mean(const float* __restrict__ part,
                            float* __restrict__ mv)
{
    const int o = threadIdx.x;
    float S = 0.0f;
    for (int tb = 0; tb < 128; ++tb)
        S = __fadd_rn(S, part[(size_t)tb * 256 + o]);
    mv[o] = S * (1.0f / 131072.0f);   // divide by 2^17: exact
}

// ---------------------------------------------------------------------------
// Pass B: per-row pairwise partial sums of fl((y-mean)^2).
// ---------------------------------------------------------------------------
__global__ __launch_bounds__(256) void pass_var(
    const float* __restrict__ x, const float* __restrict__ W,
    const float* __restrict__ mv, float* __restrict__ part)
{
    __shared__ float yrow[1024];
    __shared__ float scratch[65];
    const int tid = threadIdx.x;
    const int o  = blockIdx.x;
    const int tb = blockIdx.y;
    const int t = tb >> 4, b = tb & 15;
    const int m0 = tid * 4;

    const float mean = mv[o];
    float y0, y1, y2, y3;
    e1_row4(x, W, t, b, o, m0, y0, y1, y2, y3);
    const float d0 = __fsub_rn(y0, mean);
    const float d1 = __fsub_rn(y1, mean);
    const float d2 = __fsub_rn(y2, mean);
    const float d3 = __fsub_rn(y3, mean);
    *(float4*)&yrow[m0] = make_float4(__fmul_rn(d0, d0), __fmul_rn(d1, d1),
                                      __fmul_rn(d2, d2), __fmul_rn(d3, d3));
    __syncthreads();
    const float P = np_pairwise_1024(yrow, scratch, tid);
    if (tid == 0) part[(size_t)tb * 256 + o] = P;
}

__global__ void reduce_var(const float* __restrict__ part,
                           float* __restrict__ mv)
{
    const int o = threadIdx.x;
    float S = 0.0f;
    for (int tb = 0; tb < 128; ++tb)
        S = __fadd_rn(S, part[(size_t)tb * 256 + o]);
    const float var = S * (1.0f / 131072.0f);             // exact
    const float vp  = __fadd_rn(var, 1e-5f);
    mv[256 + o] = __fdiv_rn(1.0f, __fsqrt_rn(vp));        // fl(1/fl(sqrt))
}

// ---------------------------------------------------------------------------
// Pass C: recompute y per t, BN, LIF with state in registers, write spikes.
// grid: (o=256, b=16), 256 threads, 4 m each.
// ---------------------------------------------------------------------------
__global__ __launch_bounds__(256) void pass_lif(
    const float* __restrict__ x, const float* __restrict__ W,
    const float* __restrict__ mv,
    const float* __restrict__ gamma, const float* __restrict__ beta,
    float* __restrict__ out)
{
    const int tid = threadIdx.x;
    const int o = blockIdx.x;
    const int b = blockIdx.y;
    const int m0 = tid * 4;

    const float mean = mv[o];
    const float rs   = mv[256 + o];
    const float g    = gamma[o];
    const float be   = beta[o];

    float v0 = 0.0f, v1 = 0.0f, v2 = 0.0f, v3 = 0.0f;

    for (int t = 0; t < TT; ++t) {
        float y0, y1, y2, y3;
        e1_row4(x, W, t, b, o, m0, y0, y1, y2, y3);

        // BN: ((y - mean) * rs) * gamma + beta, each op correctly rounded
        float n0 = __fadd_rn(__fmul_rn(__fmul_rn(__fsub_rn(y0, mean), rs), g), be);
        float n1 = __fadd_rn(__fmul_rn(__fmul_rn(__fsub_rn(y1, mean), rs), g), be);
        float n2 = __fadd_rn(__fmul_rn(__fmul_rn(__fsub_rn(y2, mean), rs), g), be);
        float n3 = __fadd_rn(__fmul_rn(__fmul_rn(__fsub_rn(y3, mean), rs), g), be);

        // LIF: v = fl(v + fl(yn - v) * 0.5); halving is exact
        v0 = __fadd_rn(v0, __fmul_rn(__fsub_rn(n0, v0), 0.5f));
        v1 = __fadd_rn(v1, __fmul_rn(__fsub_rn(n1, v1), 0.5f));
        v2 = __fadd_rn(v2, __fmul_rn(__fsub_rn(n2, v2), 0.5f));
        v3 = __fadd_rn(v3, __fmul_rn(__fsub_rn(n3, v3), 0.5f));

        const bool s0 = (v0 >= 1.0f);
        const bool s1 = (v1 >= 1.0f);
        const bool s2 = (v2 >= 1.0f);
        const bool s3 = (v3 >= 1.0f);
        if (s0) v0 = 0.0f;
        if (s1) v1 = 0.0f;
        if (s2) v2 = 0.0f;
        if (s3) v3 = 0.0f;

        const size_t off = ((size_t)(t * BB + b) * CC + o) * MM + m0;
        *(float4*)(out + off) = make_float4(s0 ? 1.0f : 0.0f, s1 ? 1.0f : 0.0f,
                                            s2 ? 1.0f : 0.0f, s3 ? 1.0f : 0.0f);
    }
}

// ---------------------------------------------------------------------------
extern "C" void kernel_launch(void* const* d_in, const int* in_sizes, int n_in,
                              void* d_out, int out_size, void* d_ws, size_t ws_size,
                              hipStream_t stream)
{
    const float* x     = (const float*)d_in[0];
    const float* W     = (const float*)d_in[1];
    const float* gamma = (const float*)d_in[2];
    const float* beta  = (const float*)d_in[3];
    float* out = (float*)d_out;

    // ws layout: part[128*256] f32 (128 KB), then mv[512] f32 (mean, rs)
    float* part = (float*)d_ws;
    float* mv   = part + 128 * 256;

    pass_mean<<<dim3(256, 128), dim3(256), 0, stream>>>(x, W, part);
    reduce_mean<<<dim3(1), dim3(256), 0, stream>>>(part, mv);
    pass_var<<<dim3(256, 128), dim3(256), 0, stream>>>(x, W, mv, part);
    reduce_var<<<dim3(1), dim3(256), 0, stream>>>(part, mv);
    pass_lif<<<dim3(256, 16), dim3(256), 0, stream>>>(x, W, mv, gamma, beta, out);
}

// Round 6
// 531.261 us; speedup vs baseline: 6.7270x; 6.7270x over previous
//
#include <hip/hip_runtime.h>

// Problem constants: T=8, B=16, C_in=C_out=256, M=1024
#define TT 8
#define BB 16
#define CC 256
#define MM 1024
#define NY 33554432   // T*B*C*M elements of y

// ---------------------------------------------------------------------------
// Bit-exact numpy-fp32 semantics (verified PASS in R5):
//  - einsum('oc,tbcm->tbom'): per element, sequential ascending-c chain,
//    fl32(acc + fl32(w*x)) with separate mul/add roundings (no FMA)
//  - mean/var: numpy pairwise_sum per 1024-row + sequential fp32 carry over
//    the 128 (t,b) slabs; /2^17 exact
//  - rs = fl(1/fl(sqrt(fl(var+1e-5)))); BN affine with correctly-rounded ops
//  - LIF: v = fl(v + fl(fl(yn - v)*0.5)); s = (v>=1); hard reset
// This round: compute y ONCE (store to ws), stream it for mean/var/LIF.
// Identical bits -> identical results.
// ---------------------------------------------------------------------------

// numpy pairwise_sum over a contiguous 1024-float row (in LDS), exact.
__device__ __forceinline__ float np_pairwise_1024(
    const float* __restrict__ yrow, float* __restrict__ scratch, int tid)
{
    if (tid < 64) {
        const int blk = tid >> 3;
        const int k   = tid & 7;
        const float* p = yrow + blk * 128 + k;
        float r = p[0];
#pragma unroll
        for (int i = 1; i < 16; ++i) r = __fadd_rn(r, p[8 * i]);
        scratch[tid] = r;
    }
    __syncthreads();
    if (tid == 0) {
        float B[8];
#pragma unroll
        for (int blk = 0; blk < 8; ++blk) {
            const float* r = scratch + blk * 8;
            const float s01 = __fadd_rn(r[0], r[1]);
            const float s23 = __fadd_rn(r[2], r[3]);
            const float s45 = __fadd_rn(r[4], r[5]);
            const float s67 = __fadd_rn(r[6], r[7]);
            B[blk] = __fadd_rn(__fadd_rn(s01, s23), __fadd_rn(s45, s67));
        }
        const float c0 = __fadd_rn(B[0], B[1]);
        const float c1 = __fadd_rn(B[2], B[3]);
        const float c2 = __fadd_rn(B[4], B[5]);
        const float c3 = __fadd_rn(B[6], B[7]);
        scratch[64] = __fadd_rn(__fadd_rn(c0, c1), __fadd_rn(c2, c3));
    }
    __syncthreads();
    return scratch[64];
}

// ---------------------------------------------------------------------------
// K1: einsum, 8 o-rows per block (x float4 loaded once, reused 8x).
// grid: (og=32, tb=128), 256 threads, 4 m per thread.
// Per-element c-chain identical to the verified R5 e1_row4.
// ---------------------------------------------------------------------------
__global__ __launch_bounds__(256) void einsum_store(
    const float* __restrict__ x, const float* __restrict__ W,
    float* __restrict__ y)
{
    __shared__ float wt[CC][8];   // [c][o'] : 8 KB
    const int tid = threadIdx.x;
    const int og  = blockIdx.x;   // 0..31
    const int tb  = blockIdx.y;   // 0..127
    const int m0  = tid * 4;

#pragma unroll
    for (int i = 0; i < 8; ++i)
        wt[tid][i] = W[(size_t)(og * 8 + i) * CC + tid];
    __syncthreads();

    const float* xs = x + (size_t)tb * (CC * MM) + m0;

    float a[8][4];
#pragma unroll
    for (int i = 0; i < 8; ++i)
#pragma unroll
        for (int j = 0; j < 4; ++j) a[i][j] = 0.0f;

    for (int c = 0; c < CC; ++c) {
        const float4 xv = *(const float4*)(xs + (size_t)c * MM);
        const float4 w0 = *(const float4*)&wt[c][0];   // broadcast ds_read_b128
        const float4 w1 = *(const float4*)&wt[c][4];
        const float wv[8] = {w0.x, w0.y, w0.z, w0.w, w1.x, w1.y, w1.z, w1.w};
#pragma unroll
        for (int i = 0; i < 8; ++i) {
            a[i][0] = __fadd_rn(a[i][0], __fmul_rn(wv[i], xv.x));
            a[i][1] = __fadd_rn(a[i][1], __fmul_rn(wv[i], xv.y));
            a[i][2] = __fadd_rn(a[i][2], __fmul_rn(wv[i], xv.z));
            a[i][3] = __fadd_rn(a[i][3], __fmul_rn(wv[i], xv.w));
        }
    }

#pragma unroll
    for (int i = 0; i < 8; ++i) {
        const int o = og * 8 + i;
        *(float4*)(y + ((size_t)tb * CC + o) * MM + m0) =
            make_float4(a[i][0], a[i][1], a[i][2], a[i][3]);
    }
}

// ---------------------------------------------------------------------------
// K2: mean partials from stored y. grid (o=256, tb=128).
// ---------------------------------------------------------------------------
__global__ __launch_bounds__(256) void mean_partial_y(
    const float* __restrict__ y, float* __restrict__ part)
{
    __shared__ float yrow[1024];
    __shared__ float scratch[65];
    const int tid = threadIdx.x;
    const int o  = blockIdx.x;
    const int tb = blockIdx.y;
    const int m0 = tid * 4;

    *(float4*)&yrow[m0] = *(const float4*)(y + ((size_t)tb * CC + o) * MM + m0);
    __syncthreads();
    const float P = np_pairwise_1024(yrow, scratch, tid);
    if (tid == 0) part[(size_t)tb * 256 + o] = P;
}

__global__ void reduce_mean(const float* __restrict__ part,
                            float* __restrict__ mv)
{
    const int o = threadIdx.x;
    float S = 0.0f;
    for (int tb = 0; tb < 128; ++tb)
        S = __fadd_rn(S, part[(size_t)tb * 256 + o]);
    mv[o] = S * (1.0f / 131072.0f);   // /2^17 exact
}

// ---------------------------------------------------------------------------
// K3: var partials from stored y.
// ---------------------------------------------------------------------------
__global__ __launch_bounds__(256) void var_partial_y(
    const float* __restrict__ y, const float* __restrict__ mv,
    float* __restrict__ part)
{
    __shared__ float yrow[1024];
    __shared__ float scratch[65];
    const int tid = threadIdx.x;
    const int o  = blockIdx.x;
    const int tb = blockIdx.y;
    const int m0 = tid * 4;

    const float mean = mv[o];
    const float4 yv = *(const float4*)(y + ((size_t)tb * CC + o) * MM + m0);
    const float d0 = __fsub_rn(yv.x, mean);
    const float d1 = __fsub_rn(yv.y, mean);
    const float d2 = __fsub_rn(yv.z, mean);
    const float d3 = __fsub_rn(yv.w, mean);
    *(float4*)&yrow[m0] = make_float4(__fmul_rn(d0, d0), __fmul_rn(d1, d1),
                                      __fmul_rn(d2, d2), __fmul_rn(d3, d3));
    __syncthreads();
    const float P = np_pairwise_1024(yrow, scratch, tid);
    if (tid == 0) part[(size_t)tb * 256 + o] = P;
}

__global__ void reduce_var(const float* __restrict__ part,
                           float* __restrict__ mv)
{
    const int o = threadIdx.x;
    float S = 0.0f;
    for (int tb = 0; tb < 128; ++tb)
        S = __fadd_rn(S, part[(size_t)tb * 256 + o]);
    const float var = S * (1.0f / 131072.0f);
    const float vp  = __fadd_rn(var, 1e-5f);
    mv[256 + o] = __fdiv_rn(1.0f, __fsqrt_rn(vp));
}

// ---------------------------------------------------------------------------
// K4: BN + LIF from stored y. grid (o=256, b=16), 4 m per thread.
// ---------------------------------------------------------------------------
__global__ __launch_bounds__(256) void lif_from_y(
    const float* __restrict__ y, const float* __restrict__ mv,
    const float* __restrict__ gamma, const float* __restrict__ beta,
    float* __restrict__ out)
{
    const int tid = threadIdx.x;
    const int o = blockIdx.x;
    const int b = blockIdx.y;
    const int m0 = tid * 4;

    const float mean = mv[o];
    const float rs   = mv[256 + o];
    const float g    = gamma[o];
    const float be   = beta[o];

    float v0 = 0.0f, v1 = 0.0f, v2 = 0.0f, v3 = 0.0f;

    for (int t = 0; t < TT; ++t) {
        const size_t off = ((size_t)(t * BB + b) * CC + o) * MM + m0;
        const float4 yv = *(const float4*)(y + off);

        const float n0 = __fadd_rn(__fmul_rn(__fmul_rn(__fsub_rn(yv.x, mean), rs), g), be);
        const float n1 = __fadd_rn(__fmul_rn(__fmul_rn(__fsub_rn(yv.y, mean), rs), g), be);
        const float n2 = __fadd_rn(__fmul_rn(__fmul_rn(__fsub_rn(yv.z, mean), rs), g), be);
        const float n3 = __fadd_rn(__fmul_rn(__fmul_rn(__fsub_rn(yv.w, mean), rs), g), be);

        v0 = __fadd_rn(v0, __fmul_rn(__fsub_rn(n0, v0), 0.5f));
        v1 = __fadd_rn(v1, __fmul_rn(__fsub_rn(n1, v1), 0.5f));
        v2 = __fadd_rn(v2, __fmul_rn(__fsub_rn(n2, v2), 0.5f));
        v3 = __fadd_rn(v3, __fmul_rn(__fsub_rn(n3, v3), 0.5f));

        const bool s0 = (v0 >= 1.0f);
        const bool s1 = (v1 >= 1.0f);
        const bool s2 = (v2 >= 1.0f);
        const bool s3 = (v3 >= 1.0f);
        if (s0) v0 = 0.0f;
        if (s1) v1 = 0.0f;
        if (s2) v2 = 0.0f;
        if (s3) v3 = 0.0f;

        *(float4*)(out + off) = make_float4(s0 ? 1.0f : 0.0f, s1 ? 1.0f : 0.0f,
                                            s2 ? 1.0f : 0.0f, s3 ? 1.0f : 0.0f);
    }
}

// ---------------------------------------------------------------------------
// Fallback path (R5, verified): recompute einsum in each pass. Used only if
// ws_size cannot hold y.
// ---------------------------------------------------------------------------
__device__ __forceinline__ void e1_row4(
    const float* __restrict__ x, const float* __restrict__ W,
    int t, int b, int o, int m0,
    float& y0, float& y1, float& y2, float& y3)
{
    const float* xs = x + ((size_t)(t * BB + b) * CC) * MM + m0;
    const float* wr = W + (size_t)o * CC;
    y0 = 0.0f; y1 = 0.0f; y2 = 0.0f; y3 = 0.0f;
    for (int c = 0; c < CC; ++c) {
        const float wc = wr[c];
        const float4 xv = *(const float4*)(xs + (size_t)c * MM);
        y0 = __fadd_rn(y0, __fmul_rn(wc, xv.x));
        y1 = __fadd_rn(y1, __fmul_rn(wc, xv.y));
        y2 = __fadd_rn(y2, __fmul_rn(wc, xv.z));
        y3 = __fadd_rn(y3, __fmul_rn(wc, xv.w));
    }
}

__global__ __launch_bounds__(256) void pass_mean_fb(
    const float* __restrict__ x, const float* __restrict__ W,
    float* __restrict__ part)
{
    __shared__ float yrow[1024];
    __shared__ float scratch[65];
    const int tid = threadIdx.x;
    const int o  = blockIdx.x;
    const int tb = blockIdx.y;
    const int m0 = tid * 4;
    float y0, y1, y2, y3;
    e1_row4(x, W, tb >> 4, tb & 15, o, m0, y0, y1, y2, y3);
    *(float4*)&yrow[m0] = make_float4(y0, y1, y2, y3);
    __syncthreads();
    const float P = np_pairwise_1024(yrow, scratch, tid);
    if (tid == 0) part[(size_t)tb * 256 + o] = P;
}

__global__ __launch_bounds__(256) void pass_var_fb(
    const float* __restrict__ x, const float* __restrict__ W,
    const float* __restrict__ mv, float* __restrict__ part)
{
    __shared__ float yrow[1024];
    __shared__ float scratch[65];
    const int tid = threadIdx.x;
    const int o  = blockIdx.x;
    const int tb = blockIdx.y;
    const int m0 = tid * 4;
    const float mean = mv[o];
    float y0, y1, y2, y3;
    e1_row4(x, W, tb >> 4, tb & 15, o, m0, y0, y1, y2, y3);
    const float d0 = __fsub_rn(y0, mean);
    const float d1 = __fsub_rn(y1, mean);
    const float d2 = __fsub_rn(y2, mean);
    const float d3 = __fsub_rn(y3, mean);
    *(float4*)&yrow[m0] = make_float4(__fmul_rn(d0, d0), __fmul_rn(d1, d1),
                                      __fmul_rn(d2, d2), __fmul_rn(d3, d3));
    __syncthreads();
    const float P = np_pairwise_1024(yrow, scratch, tid);
    if (tid == 0) part[(size_t)tb * 256 + o] = P;
}

__global__ __launch_bounds__(256) void pass_lif_fb(
    const float* __restrict__ x, const float* __restrict__ W,
    const float* __restrict__ mv,
    const float* __restrict__ gamma, const float* __restrict__ beta,
    float* __restrict__ out)
{
    const int tid = threadIdx.x;
    const int o = blockIdx.x;
    const int b = blockIdx.y;
    const int m0 = tid * 4;
    const float mean = mv[o];
    const float rs   = mv[256 + o];
    const float g    = gamma[o];
    const float be   = beta[o];
    float v0 = 0.0f, v1 = 0.0f, v2 = 0.0f, v3 = 0.0f;
    for (int t = 0; t < TT; ++t) {
        float y0, y1, y2, y3;
        e1_row4(x, W, t, b, o, m0, y0, y1, y2, y3);
        const float n0 = __fadd_rn(__fmul_rn(__fmul_rn(__fsub_rn(y0, mean), rs), g), be);
        const float n1 = __fadd_rn(__fmul_rn(__fmul_rn(__fsub_rn(y1, mean), rs), g), be);
        const float n2 = __fadd_rn(__fmul_rn(__fmul_rn(__fsub_rn(y2, mean), rs), g), be);
        const float n3 = __fadd_rn(__fmul_rn(__fmul_rn(__fsub_rn(y3, mean), rs), g), be);
        v0 = __fadd_rn(v0, __fmul_rn(__fsub_rn(n0, v0), 0.5f));
        v1 = __fadd_rn(v1, __fmul_rn(__fsub_rn(n1, v1), 0.5f));
        v2 = __fadd_rn(v2, __fmul_rn(__fsub_rn(n2, v2), 0.5f));
        v3 = __fadd_rn(v3, __fmul_rn(__fsub_rn(n3, v3), 0.5f));
        const bool s0 = (v0 >= 1.0f);
        const bool s1 = (v1 >= 1.0f);
        const bool s2 = (v2 >= 1.0f);
        const bool s3 = (v3 >= 1.0f);
        if (s0) v0 = 0.0f;
        if (s1) v1 = 0.0f;
        if (s2) v2 = 0.0f;
        if (s3) v3 = 0.0f;
        const size_t off = ((size_t)(t * BB + b) * CC + o) * MM + m0;
        *(float4*)(out + off) = make_float4(s0 ? 1.0f : 0.0f, s1 ? 1.0f : 0.0f,
                                            s2 ? 1.0f : 0.0f, s3 ? 1.0f : 0.0f);
    }
}

// ---------------------------------------------------------------------------
extern "C" void kernel_launch(void* const* d_in, const int* in_sizes, int n_in,
                              void* d_out, int out_size, void* d_ws, size_t ws_size,
                              hipStream_t stream)
{
    const float* x     = (const float*)d_in[0];
    const float* W     = (const float*)d_in[1];
    const float* gamma = (const float*)d_in[2];
    const float* beta  = (const float*)d_in[3];
    float* out = (float*)d_out;

    const size_t need = ((size_t)NY + 128 * 256 + 512) * sizeof(float);

    if (ws_size >= need) {
        float* y    = (float*)d_ws;
        float* part = y + NY;
        float* mv   = part + 128 * 256;

        einsum_store<<<dim3(32, 128), dim3(256), 0, stream>>>(x, W, y);
        mean_partial_y<<<dim3(256, 128), dim3(256), 0, stream>>>(y, part);
        reduce_mean<<<dim3(1), dim3(256), 0, stream>>>(part, mv);
        var_partial_y<<<dim3(256, 128), dim3(256), 0, stream>>>(y, mv, part);
        reduce_var<<<dim3(1), dim3(256), 0, stream>>>(part, mv);
        lif_from_y<<<dim3(256, 16), dim3(256), 0, stream>>>(y, mv, gamma, beta, out);
    } else {
        float* part = (float*)d_ws;
        float* mv   = part + 128 * 256;
        pass_mean_fb<<<dim3(256, 128), dim3(256), 0, stream>>>(x, W, part);
        reduce_mean<<<dim3(1), dim3(256), 0, stream>>>(part, mv);
        pass_var_fb<<<dim3(256, 128), dim3(256), 0, stream>>>(x, W, mv, part);
        reduce_var<<<dim3(1), dim3(256), 0, stream>>>(part, mv);
        pass_lif_fb<<<dim3(256, 16), dim3(256), 0, stream>>>(x, W, mv, gamma, beta, out);
    }
}

// Round 8
// 506.552 us; speedup vs baseline: 7.0551x; 1.0488x over previous
//
#include <hip/hip_runtime.h>

// Problem constants: T=8, B=16, C_in=C_out=256, M=1024
#define TT 8
#define BB 16
#define CC 256
#define MM 1024
#define NY 33554432   // T*B*C*M elements of y

// ---------------------------------------------------------------------------
// Bit-exact numpy-fp32 semantics (verified PASS in R5/R6 incl. replay checks):
//  - einsum('oc,tbcm->tbom'): per element, sequential ascending-c chain,
//    fl32(acc + fl32(w*x)) with separate mul/add roundings (no FMA)
//  - mean/var: numpy pairwise_sum per 1024-row + sequential fp32 carry over
//    the 128 (t,b) slabs; /2^17 exact
//  - rs = fl(1/fl(sqrt(fl(var+1e-5)))); BN affine with correctly-rounded ops
//  - LIF: v = fl(v + fl(fl(yn - v)*0.5)); s = (v>=1); hard reset
// R8 = R6 pipeline verbatim (R7's fused-mean einsum showed a timing-sensitive
// divergence on graph replay -> reverted), plus ONE change: XCD-aware block
// swizzle on einsum_store so each x slab is fetched by exactly one XCD's L2.
// ---------------------------------------------------------------------------

// numpy pairwise_sum over a contiguous 1024-float row (in LDS), exact.
__device__ __forceinline__ float np_pairwise_1024(
    const float* __restrict__ yrow, float* __restrict__ scratch, int tid)
{
    if (tid < 64) {
        const int blk = tid >> 3;
        const int k   = tid & 7;
        const float* p = yrow + blk * 128 + k;
        float r = p[0];
#pragma unroll
        for (int i = 1; i < 16; ++i) r = __fadd_rn(r, p[8 * i]);
        scratch[tid] = r;
    }
    __syncthreads();
    if (tid == 0) {
        float B[8];
#pragma unroll
        for (int blk = 0; blk < 8; ++blk) {
            const float* r = scratch + blk * 8;
            const float s01 = __fadd_rn(r[0], r[1]);
            const float s23 = __fadd_rn(r[2], r[3]);
            const float s45 = __fadd_rn(r[4], r[5]);
            const float s67 = __fadd_rn(r[6], r[7]);
            B[blk] = __fadd_rn(__fadd_rn(s01, s23), __fadd_rn(s45, s67));
        }
        const float c0 = __fadd_rn(B[0], B[1]);
        const float c1 = __fadd_rn(B[2], B[3]);
        const float c2 = __fadd_rn(B[4], B[5]);
        const float c3 = __fadd_rn(B[6], B[7]);
        scratch[64] = __fadd_rn(__fadd_rn(c0, c1), __fadd_rn(c2, c3));
    }
    __syncthreads();
    return scratch[64];
}

// ---------------------------------------------------------------------------
// K1: einsum, 8 o-rows per block (x float4 loaded once, reused 8x).
// Grid: 4096 linear. XCD swizzle: xcd = lin&7 (blocks round-robin across
// XCDs), j = lin>>3; og = j&31 (fastest -> the 32 blocks of one slab are
// dispatched consecutively on one XCD); tb = xcd*16 + (j>>5).
// Per-element c-chain identical to verified R5/R6.
// ---------------------------------------------------------------------------
__global__ __launch_bounds__(256) void einsum_store(
    const float* __restrict__ x, const float* __restrict__ W,
    float* __restrict__ y)
{
    __shared__ float wt[CC][8];   // [c][o'] : 8 KB
    const int tid = threadIdx.x;
    const int lin = blockIdx.x;          // 0..4095
    const int xcd = lin & 7;
    const int j   = lin >> 3;            // 0..511
    const int og  = j & 31;              // o block: 8 channels
    const int tb  = xcd * 16 + (j >> 5); // 0..127
    const int m0  = tid * 4;

#pragma unroll
    for (int i = 0; i < 8; ++i)
        wt[tid][i] = W[(size_t)(og * 8 + i) * CC + tid];
    __syncthreads();

    const float* xs = x + (size_t)tb * (CC * MM) + m0;

    float a[8][4];
#pragma unroll
    for (int i = 0; i < 8; ++i)
#pragma unroll
        for (int q = 0; q < 4; ++q) a[i][q] = 0.0f;

    for (int c = 0; c < CC; ++c) {
        const float4 xv = *(const float4*)(xs + (size_t)c * MM);
        const float4 w0 = *(const float4*)&wt[c][0];   // broadcast ds_read_b128
        const float4 w1 = *(const float4*)&wt[c][4];
        const float wv[8] = {w0.x, w0.y, w0.z, w0.w, w1.x, w1.y, w1.z, w1.w};
#pragma unroll
        for (int i = 0; i < 8; ++i) {
            a[i][0] = __fadd_rn(a[i][0], __fmul_rn(wv[i], xv.x));
            a[i][1] = __fadd_rn(a[i][1], __fmul_rn(wv[i], xv.y));
            a[i][2] = __fadd_rn(a[i][2], __fmul_rn(wv[i], xv.z));
            a[i][3] = __fadd_rn(a[i][3], __fmul_rn(wv[i], xv.w));
        }
    }

#pragma unroll
    for (int i = 0; i < 8; ++i) {
        const int o = og * 8 + i;
        *(float4*)(y + ((size_t)tb * CC + o) * MM + m0) =
            make_float4(a[i][0], a[i][1], a[i][2], a[i][3]);
    }
}

// ---------------------------------------------------------------------------
// K2: mean partials from stored y. grid (o=256, tb=128).
// ---------------------------------------------------------------------------
__global__ __launch_bounds__(256) void mean_partial_y(
    const float* __restrict__ y, float* __restrict__ part)
{
    __shared__ float yrow[1024];
    __shared__ float scratch[65];
    const int tid = threadIdx.x;
    const int o  = blockIdx.x;
    const int tb = blockIdx.y;
    const int m0 = tid * 4;

    *(float4*)&yrow[m0] = *(const float4*)(y + ((size_t)tb * CC + o) * MM + m0);
    __syncthreads();
    const float P = np_pairwise_1024(yrow, scratch, tid);
    if (tid == 0) part[(size_t)tb * 256 + o] = P;
}

__global__ void reduce_mean(const float* __restrict__ part,
                            float* __restrict__ mv)
{
    const int o = threadIdx.x;
    float S = 0.0f;
    for (int tb = 0; tb < 128; ++tb)
        S = __fadd_rn(S, part[(size_t)tb * 256 + o]);
    mv[o] = S * (1.0f / 131072.0f);   // /2^17 exact
}

// ---------------------------------------------------------------------------
// K3: var partials from stored y.
// ---------------------------------------------------------------------------
__global__ __launch_bounds__(256) void var_partial_y(
    const float* __restrict__ y, const float* __restrict__ mv,
    float* __restrict__ part)
{
    __shared__ float yrow[1024];
    __shared__ float scratch[65];
    const int tid = threadIdx.x;
    const int o  = blockIdx.x;
    const int tb = blockIdx.y;
    const int m0 = tid * 4;

    const float mean = mv[o];
    const float4 yv = *(const float4*)(y + ((size_t)tb * CC + o) * MM + m0);
    const float d0 = __fsub_rn(yv.x, mean);
    const float d1 = __fsub_rn(yv.y, mean);
    const float d2 = __fsub_rn(yv.z, mean);
    const float d3 = __fsub_rn(yv.w, mean);
    *(float4*)&yrow[m0] = make_float4(__fmul_rn(d0, d0), __fmul_rn(d1, d1),
                                      __fmul_rn(d2, d2), __fmul_rn(d3, d3));
    __syncthreads();
    const float P = np_pairwise_1024(yrow, scratch, tid);
    if (tid == 0) part[(size_t)tb * 256 + o] = P;
}

__global__ void reduce_var(const float* __restrict__ part,
                           float* __restrict__ mv)
{
    const int o = threadIdx.x;
    float S = 0.0f;
    for (int tb = 0; tb < 128; ++tb)
        S = __fadd_rn(S, part[(size_t)tb * 256 + o]);
    const float var = S * (1.0f / 131072.0f);
    const float vp  = __fadd_rn(var, 1e-5f);
    mv[256 + o] = __fdiv_rn(1.0f, __fsqrt_rn(vp));
}

// ---------------------------------------------------------------------------
// K4: BN + LIF from stored y. grid (o=256, b=16), 4 m per thread.
// ---------------------------------------------------------------------------
__global__ __launch_bounds__(256) void lif_from_y(
    const float* __restrict__ y, const float* __restrict__ mv,
    const float* __restrict__ gamma, const float* __restrict__ beta,
    float* __restrict__ out)
{
    const int tid = threadIdx.x;
    const int o = blockIdx.x;
    const int b = blockIdx.y;
    const int m0 = tid * 4;

    const float mean = mv[o];
    const float rs   = mv[256 + o];
    const float g    = gamma[o];
    const float be   = beta[o];

    float v0 = 0.0f, v1 = 0.0f, v2 = 0.0f, v3 = 0.0f;

    for (int t = 0; t < TT; ++t) {
        const size_t off = ((size_t)(t * BB + b) * CC + o) * MM + m0;
        const float4 yv = *(const float4*)(y + off);

        const float n0 = __fadd_rn(__fmul_rn(__fmul_rn(__fsub_rn(yv.x, mean), rs), g), be);
        const float n1 = __fadd_rn(__fmul_rn(__fmul_rn(__fsub_rn(yv.y, mean), rs), g), be);
        const float n2 = __fadd_rn(__fmul_rn(__fmul_rn(__fsub_rn(yv.z, mean), rs), g), be);
        const float n3 = __fadd_rn(__fmul_rn(__fmul_rn(__fsub_rn(yv.w, mean), rs), g), be);

        v0 = __fadd_rn(v0, __fmul_rn(__fsub_rn(n0, v0), 0.5f));
        v1 = __fadd_rn(v1, __fmul_rn(__fsub_rn(n1, v1), 0.5f));
        v2 = __fadd_rn(v2, __fmul_rn(__fsub_rn(n2, v2), 0.5f));
        v3 = __fadd_rn(v3, __fmul_rn(__fsub_rn(n3, v3), 0.5f));

        const bool s0 = (v0 >= 1.0f);
        const bool s1 = (v1 >= 1.0f);
        const bool s2 = (v2 >= 1.0f);
        const bool s3 = (v3 >= 1.0f);
        if (s0) v0 = 0.0f;
        if (s1) v1 = 0.0f;
        if (s2) v2 = 0.0f;
        if (s3) v3 = 0.0f;

        *(float4*)(out + off) = make_float4(s0 ? 1.0f : 0.0f, s1 ? 1.0f : 0.0f,
                                            s2 ? 1.0f : 0.0f, s3 ? 1.0f : 0.0f);
    }
}

// ---------------------------------------------------------------------------
// Fallback path (R5, verified): recompute einsum in each pass. Only used if
// ws cannot hold y (not expected on this harness).
// ---------------------------------------------------------------------------
__device__ __forceinline__ void e1_row4(
    const float* __restrict__ x, const float* __restrict__ W,
    int t, int b, int o, int m0,
    float& y0, float& y1, float& y2, float& y3)
{
    const float* xs = x + ((size_t)(t * BB + b) * CC) * MM + m0;
    const float* wr = W + (size_t)o * CC;
    y0 = 0.0f; y1 = 0.0f; y2 = 0.0f; y3 = 0.0f;
    for (int c = 0; c < CC; ++c) {
        const float wc = wr[c];
        const float4 xv = *(const float4*)(xs + (size_t)c * MM);
        y0 = __fadd_rn(y0, __fmul_rn(wc, xv.x));
        y1 = __fadd_rn(y1, __fmul_rn(wc, xv.y));
        y2 = __fadd_rn(y2, __fmul_rn(wc, xv.z));
        y3 = __fadd_rn(y3, __fmul_rn(wc, xv.w));
    }
}

__global__ __launch_bounds__(256) void pass_mean_fb(
    const float* __restrict__ x, const float* __restrict__ W,
    float* __restrict__ part)
{
    __shared__ float yrow[1024];
    __shared__ float scratch[65];
    const int tid = threadIdx.x;
    const int o  = blockIdx.x;
    const int tb = blockIdx.y;
    const int m0 = tid * 4;
    float y0, y1, y2, y3;
    e1_row4(x, W, tb >> 4, tb & 15, o, m0, y0, y1, y2, y3);
    *(float4*)&yrow[m0] = make_float4(y0, y1, y2, y3);
    __syncthreads();
    const float P = np_pairwise_1024(yrow, scratch, tid);
    if (tid == 0) part[(size_t)tb * 256 + o] = P;
}

__global__ __launch_bounds__(256) void pass_var_fb(
    const float* __restrict__ x, const float* __restrict__ W,
    const float* __restrict__ mv, float* __restrict__ part)
{
    __shared__ float yrow[1024];
    __shared__ float scratch[65];
    const int tid = threadIdx.x;
    const int o  = blockIdx.x;
    const int tb = blockIdx.y;
    const int m0 = tid * 4;
    const float mean = mv[o];
    float y0, y1, y2, y3;
    e1_row4(x, W, tb >> 4, tb & 15, o, m0, y0, y1, y2, y3);
    const float d0 = __fsub_rn(y0, mean);
    const float d1 = __fsub_rn(y1, mean);
    const float d2 = __fsub_rn(y2, mean);
    const float d3 = __fsub_rn(y3, mean);
    *(float4*)&yrow[m0] = make_float4(__fmul_rn(d0, d0), __fmul_rn(d1, d1),
                                      __fmul_rn(d2, d2), __fmul_rn(d3, d3));
    __syncthreads();
    const float P = np_pairwise_1024(yrow, scratch, tid);
    if (tid == 0) part[(size_t)tb * 256 + o] = P;
}

__global__ __launch_bounds__(256) void pass_lif_fb(
    const float* __restrict__ x, const float* __restrict__ W,
    const float* __restrict__ mv,
    const float* __restrict__ gamma, const float* __restrict__ beta,
    float* __restrict__ out)
{
    const int tid = threadIdx.x;
    const int o = blockIdx.x;
    const int b = blockIdx.y;
    const int m0 = tid * 4;
    const float mean = mv[o];
    const float rs   = mv[256 + o];
    const float g    = gamma[o];
    const float be   = beta[o];
    float v0 = 0.0f, v1 = 0.0f, v2 = 0.0f, v3 = 0.0f;
    for (int t = 0; t < TT; ++t) {
        float y0, y1, y2, y3;
        e1_row4(x, W, t, b, o, m0, y0, y1, y2, y3);
        const float n0 = __fadd_rn(__fmul_rn(__fmul_rn(__fsub_rn(y0, mean), rs), g), be);
        const float n1 = __fadd_rn(__fmul_rn(__fmul_rn(__fsub_rn(y1, mean), rs), g), be);
        const float n2 = __fadd_rn(__fmul_rn(__fmul_rn(__fsub_rn(y2, mean), rs), g), be);
        const float n3 = __fadd_rn(__fmul_rn(__fmul_rn(__fsub_rn(y3, mean), rs), g), be);
        v0 = __fadd_rn(v0, __fmul_rn(__fsub_rn(n0, v0), 0.5f));
        v1 = __fadd_rn(v1, __fmul_rn(__fsub_rn(n1, v1), 0.5f));
        v2 = __fadd_rn(v2, __fmul_rn(__fsub_rn(n2, v2), 0.5f));
        v3 = __fadd_rn(v3, __fmul_rn(__fsub_rn(n3, v3), 0.5f));
        const bool s0 = (v0 >= 1.0f);
        const bool s1 = (v1 >= 1.0f);
        const bool s2 = (v2 >= 1.0f);
        const bool s3 = (v3 >= 1.0f);
        if (s0) v0 = 0.0f;
        if (s1) v1 = 0.0f;
        if (s2) v2 = 0.0f;
        if (s3) v3 = 0.0f;
        const size_t off = ((size_t)(t * BB + b) * CC + o) * MM + m0;
        *(float4*)(out + off) = make_float4(s0 ? 1.0f : 0.0f, s1 ? 1.0f : 0.0f,
                                            s2 ? 1.0f : 0.0f, s3 ? 1.0f : 0.0f);
    }
}

// ---------------------------------------------------------------------------
extern "C" void kernel_launch(void* const* d_in, const int* in_sizes, int n_in,
                              void* d_out, int out_size, void* d_ws, size_t ws_size,
                              hipStream_t stream)
{
    const float* x     = (const float*)d_in[0];
    const float* W     = (const float*)d_in[1];
    const float* gamma = (const float*)d_in[2];
    const float* beta  = (const float*)d_in[3];
    float* out = (float*)d_out;

    const size_t need = ((size_t)NY + 128 * 256 + 512) * sizeof(float);

    if (ws_size >= need) {
        float* y    = (float*)d_ws;
        float* part = y + NY;
        float* mv   = part + 128 * 256;

        einsum_store<<<dim3(4096), dim3(256), 0, stream>>>(x, W, y);
        mean_partial_y<<<dim3(256, 128), dim3(256), 0, stream>>>(y, part);
        reduce_mean<<<dim3(1), dim3(256), 0, stream>>>(part, mv);
        var_partial_y<<<dim3(256, 128), dim3(256), 0, stream>>>(y, mv, part);
        reduce_var<<<dim3(1), dim3(256), 0, stream>>>(part, mv);
        lif_from_y<<<dim3(256, 16), dim3(256), 0, stream>>>(y, mv, gamma, beta, out);
    } else {
        float* part = (float*)d_ws;
        float* mv   = part + 128 * 256;
        pass_mean_fb<<<dim3(256, 128), dim3(256), 0, stream>>>(x, W, part);
        reduce_mean<<<dim3(1), dim3(256), 0, stream>>>(part, mv);
        pass_var_fb<<<dim3(256, 128), dim3(256), 0, stream>>>(x, W, mv, part);
        reduce_var<<<dim3(1), dim3(256), 0, stream>>>(part, mv);
        pass_lif_fb<<<dim3(256, 16), dim3(256), 0, stream>>>(x, W, mv, gamma, beta, out);
    }
}

// Round 9
// 478.787 us; speedup vs baseline: 7.4643x; 1.0580x over previous
//
#include <hip/hip_runtime.h>

// Problem constants: T=8, B=16, C_in=C_out=256, M=1024
#define TT 8
#define BB 16
#define CC 256
#define MM 1024
#define NY 33554432   // T*B*C*M elements of y

// ---------------------------------------------------------------------------
// Bit-exact numpy-fp32 semantics (verified PASS R5/R6/R8 incl. replay checks):
//  - einsum('oc,tbcm->tbom'): per element, sequential ascending-c chain,
//    fl32(acc + fl32(w*x)) with separate mul/add roundings (no FMA)
//  - mean/var: numpy pairwise_sum per 1024-row + sequential fp32 carry over
//    the 128 (t,b) slabs; /2^17 exact
//  - rs = fl(1/fl(sqrt(fl(var+1e-5)))); BN affine with correctly-rounded ops
//  - LIF: v = fl(v + fl(fl(yn - v)*0.5)); s = (v>=1); hard reset
// R9 = R8 graph verbatim; within-kernel changes only:
//  - einsum: 16 o/block + register double-buffered x prefetch
//  - mean/var partials: 4 rows per block (wave-group per row)
// ---------------------------------------------------------------------------

// ---------------------------------------------------------------------------
// K1: einsum, 16 o-rows per block, x prefetched one 4-c group ahead.
// Grid: 2048 linear. XCD swizzle: xcd = lin&7; j = lin>>3; og = j&15
// (fastest -> the 16 blocks of one slab dispatched consecutively per XCD);
// tb = xcd*16 + (j>>4). Per-element c-chain identical to verified R5/R6/R8.
// ---------------------------------------------------------------------------
__global__ __launch_bounds__(256) void einsum_store(
    const float* __restrict__ x, const float* __restrict__ W,
    float* __restrict__ y)
{
    __shared__ float wt[CC][16];   // [c][o'] : 16 KB
    const int tid = threadIdx.x;
    const int lin = blockIdx.x;          // 0..2047
    const int xcd = lin & 7;
    const int j   = lin >> 3;            // 0..255
    const int og  = j & 15;              // o block: 16 channels
    const int tb  = xcd * 16 + (j >> 4); // 0..127
    const int m0  = tid * 4;

#pragma unroll
    for (int i = 0; i < 16; ++i)
        wt[tid][i] = W[(size_t)(og * 16 + i) * CC + tid];
    __syncthreads();

    const float* xs = x + (size_t)tb * (CC * MM) + m0;

    float a[16][4];
#pragma unroll
    for (int i = 0; i < 16; ++i)
#pragma unroll
        for (int q = 0; q < 4; ++q) a[i][q] = 0.0f;

    float4 xb[4];
#pragma unroll
    for (int q = 0; q < 4; ++q)
        xb[q] = *(const float4*)(xs + (size_t)q * MM);

    for (int cb = 0; cb < CC; cb += 4) {
        float4 xn[4];
        const bool more = (cb + 4 < CC);
        if (more) {
#pragma unroll
            for (int q = 0; q < 4; ++q)
                xn[q] = *(const float4*)(xs + (size_t)(cb + 4 + q) * MM);
        }
#pragma unroll
        for (int q = 0; q < 4; ++q) {
            const int c = cb + q;
            const float4 w0 = *(const float4*)&wt[c][0];    // broadcast reads
            const float4 w1 = *(const float4*)&wt[c][4];
            const float4 w2 = *(const float4*)&wt[c][8];
            const float4 w3 = *(const float4*)&wt[c][12];
            const float wv[16] = {w0.x, w0.y, w0.z, w0.w,
                                  w1.x, w1.y, w1.z, w1.w,
                                  w2.x, w2.y, w2.z, w2.w,
                                  w3.x, w3.y, w3.z, w3.w};
#pragma unroll
            for (int i = 0; i < 16; ++i) {
                a[i][0] = __fadd_rn(a[i][0], __fmul_rn(wv[i], xb[q].x));
                a[i][1] = __fadd_rn(a[i][1], __fmul_rn(wv[i], xb[q].y));
                a[i][2] = __fadd_rn(a[i][2], __fmul_rn(wv[i], xb[q].z));
                a[i][3] = __fadd_rn(a[i][3], __fmul_rn(wv[i], xb[q].w));
            }
        }
        if (more) {
#pragma unroll
            for (int q = 0; q < 4; ++q) xb[q] = xn[q];
        }
    }

#pragma unroll
    for (int i = 0; i < 16; ++i) {
        const int o = og * 16 + i;
        *(float4*)(y + ((size_t)tb * CC + o) * MM + m0) =
            make_float4(a[i][0], a[i][1], a[i][2], a[i][3]);
    }
}

// ---------------------------------------------------------------------------
// K2: mean partials from stored y, 4 rows per block (one per 64-lane group).
// Flat row = tb*256 + o  ->  y offset row*1024, part[row]. Grid 8192.
// Pairwise chain identical to verified np_pairwise_1024.
// ---------------------------------------------------------------------------
__global__ __launch_bounds__(256) void mean_partial_y(
    const float* __restrict__ y, float* __restrict__ part)
{
    __shared__ float yrow[4][1024];
    __shared__ float scratch[4][64];
    const int tid  = threadIdx.x;
    const int g    = tid >> 6;
    const int lane = tid & 63;
    const size_t row = (size_t)blockIdx.x * 4 + g;   // 0..32767
    const float* yr = y + row * MM;

#pragma unroll
    for (int q = 0; q < 4; ++q)
        *(float4*)&yrow[g][q * 256 + lane * 4] =
            *(const float4*)(yr + q * 256 + lane * 4);
    __syncthreads();

    {
        const int blk = lane >> 3;
        const int k   = lane & 7;
        const float* p = &yrow[g][blk * 128 + k];
        float r = p[0];
#pragma unroll
        for (int i = 1; i < 16; ++i) r = __fadd_rn(r, p[8 * i]);
        scratch[g][lane] = r;
    }
    __syncthreads();

    if (lane == 0) {
        float B[8];
#pragma unroll
        for (int b2 = 0; b2 < 8; ++b2) {
            const float* r = &scratch[g][b2 * 8];
            const float s01 = __fadd_rn(r[0], r[1]);
            const float s23 = __fadd_rn(r[2], r[3]);
            const float s45 = __fadd_rn(r[4], r[5]);
            const float s67 = __fadd_rn(r[6], r[7]);
            B[b2] = __fadd_rn(__fadd_rn(s01, s23), __fadd_rn(s45, s67));
        }
        const float c0 = __fadd_rn(B[0], B[1]);
        const float c1 = __fadd_rn(B[2], B[3]);
        const float c2 = __fadd_rn(B[4], B[5]);
        const float c3 = __fadd_rn(B[6], B[7]);
        part[row] = __fadd_rn(__fadd_rn(c0, c1), __fadd_rn(c2, c3));
    }
}

__global__ void reduce_mean(const float* __restrict__ part,
                            float* __restrict__ mv)
{
    const int o = threadIdx.x;
    float S = 0.0f;
    for (int tb = 0; tb < 128; ++tb)
        S = __fadd_rn(S, part[(size_t)tb * 256 + o]);
    mv[o] = S * (1.0f / 131072.0f);   // /2^17 exact
}

// ---------------------------------------------------------------------------
// K3: var partials from stored y, 4 rows per block.
// ---------------------------------------------------------------------------
__global__ __launch_bounds__(256) void var_partial_y(
    const float* __restrict__ y, const float* __restrict__ mv,
    float* __restrict__ part)
{
    __shared__ float yrow[4][1024];
    __shared__ float scratch[4][64];
    const int tid  = threadIdx.x;
    const int g    = tid >> 6;
    const int lane = tid & 63;
    const size_t row = (size_t)blockIdx.x * 4 + g;
    const float* yr = y + row * MM;
    const float mean = mv[row & 255];

#pragma unroll
    for (int q = 0; q < 4; ++q) {
        const float4 yv = *(const float4*)(yr + q * 256 + lane * 4);
        const float d0 = __fsub_rn(yv.x, mean);
        const float d1 = __fsub_rn(yv.y, mean);
        const float d2 = __fsub_rn(yv.z, mean);
        const float d3 = __fsub_rn(yv.w, mean);
        *(float4*)&yrow[g][q * 256 + lane * 4] =
            make_float4(__fmul_rn(d0, d0), __fmul_rn(d1, d1),
                        __fmul_rn(d2, d2), __fmul_rn(d3, d3));
    }
    __syncthreads();

    {
        const int blk = lane >> 3;
        const int k   = lane & 7;
        const float* p = &yrow[g][blk * 128 + k];
        float r = p[0];
#pragma unroll
        for (int i = 1; i < 16; ++i) r = __fadd_rn(r, p[8 * i]);
        scratch[g][lane] = r;
    }
    __syncthreads();

    if (lane == 0) {
        float B[8];
#pragma unroll
        for (int b2 = 0; b2 < 8; ++b2) {
            const float* r = &scratch[g][b2 * 8];
            const float s01 = __fadd_rn(r[0], r[1]);
            const float s23 = __fadd_rn(r[2], r[3]);
            const float s45 = __fadd_rn(r[4], r[5]);
            const float s67 = __fadd_rn(r[6], r[7]);
            B[b2] = __fadd_rn(__fadd_rn(s01, s23), __fadd_rn(s45, s67));
        }
        const float c0 = __fadd_rn(B[0], B[1]);
        const float c1 = __fadd_rn(B[2], B[3]);
        const float c2 = __fadd_rn(B[4], B[5]);
        const float c3 = __fadd_rn(B[6], B[7]);
        part[row] = __fadd_rn(__fadd_rn(c0, c1), __fadd_rn(c2, c3));
    }
}

__global__ void reduce_var(const float* __restrict__ part,
                           float* __restrict__ mv)
{
    const int o = threadIdx.x;
    float S = 0.0f;
    for (int tb = 0; tb < 128; ++tb)
        S = __fadd_rn(S, part[(size_t)tb * 256 + o]);
    const float var = S * (1.0f / 131072.0f);
    const float vp  = __fadd_rn(var, 1e-5f);
    mv[256 + o] = __fdiv_rn(1.0f, __fsqrt_rn(vp));
}

// ---------------------------------------------------------------------------
// K4: BN + LIF from stored y. grid (o=256, b=16), 4 m per thread. (R8 verbatim)
// ---------------------------------------------------------------------------
__global__ __launch_bounds__(256) void lif_from_y(
    const float* __restrict__ y, const float* __restrict__ mv,
    const float* __restrict__ gamma, const float* __restrict__ beta,
    float* __restrict__ out)
{
    const int tid = threadIdx.x;
    const int o = blockIdx.x;
    const int b = blockIdx.y;
    const int m0 = tid * 4;

    const float mean = mv[o];
    const float rs   = mv[256 + o];
    const float g    = gamma[o];
    const float be   = beta[o];

    float v0 = 0.0f, v1 = 0.0f, v2 = 0.0f, v3 = 0.0f;

    for (int t = 0; t < TT; ++t) {
        const size_t off = ((size_t)(t * BB + b) * CC + o) * MM + m0;
        const float4 yv = *(const float4*)(y + off);

        const float n0 = __fadd_rn(__fmul_rn(__fmul_rn(__fsub_rn(yv.x, mean), rs), g), be);
        const float n1 = __fadd_rn(__fmul_rn(__fmul_rn(__fsub_rn(yv.y, mean), rs), g), be);
        const float n2 = __fadd_rn(__fmul_rn(__fmul_rn(__fsub_rn(yv.z, mean), rs), g), be);
        const float n3 = __fadd_rn(__fmul_rn(__fmul_rn(__fsub_rn(yv.w, mean), rs), g), be);

        v0 = __fadd_rn(v0, __fmul_rn(__fsub_rn(n0, v0), 0.5f));
        v1 = __fadd_rn(v1, __fmul_rn(__fsub_rn(n1, v1), 0.5f));
        v2 = __fadd_rn(v2, __fmul_rn(__fsub_rn(n2, v2), 0.5f));
        v3 = __fadd_rn(v3, __fmul_rn(__fsub_rn(n3, v3), 0.5f));

        const bool s0 = (v0 >= 1.0f);
        const bool s1 = (v1 >= 1.0f);
        const bool s2 = (v2 >= 1.0f);
        const bool s3 = (v3 >= 1.0f);
        if (s0) v0 = 0.0f;
        if (s1) v1 = 0.0f;
        if (s2) v2 = 0.0f;
        if (s3) v3 = 0.0f;

        *(float4*)(out + off) = make_float4(s0 ? 1.0f : 0.0f, s1 ? 1.0f : 0.0f,
                                            s2 ? 1.0f : 0.0f, s3 ? 1.0f : 0.0f);
    }
}

// ---------------------------------------------------------------------------
// Fallback path (R5, verified): recompute einsum in each pass. Only used if
// ws cannot hold y (not expected on this harness).
// ---------------------------------------------------------------------------
__device__ __forceinline__ void e1_row4(
    const float* __restrict__ x, const float* __restrict__ W,
    int t, int b, int o, int m0,
    float& y0, float& y1, float& y2, float& y3)
{
    const float* xs = x + ((size_t)(t * BB + b) * CC) * MM + m0;
    const float* wr = W + (size_t)o * CC;
    y0 = 0.0f; y1 = 0.0f; y2 = 0.0f; y3 = 0.0f;
    for (int c = 0; c < CC; ++c) {
        const float wc = wr[c];
        const float4 xv = *(const float4*)(xs + (size_t)c * MM);
        y0 = __fadd_rn(y0, __fmul_rn(wc, xv.x));
        y1 = __fadd_rn(y1, __fmul_rn(wc, xv.y));
        y2 = __fadd_rn(y2, __fmul_rn(wc, xv.z));
        y3 = __fadd_rn(y3, __fmul_rn(wc, xv.w));
    }
}

__device__ __forceinline__ float np_pairwise_1024(
    const float* __restrict__ yrow, float* __restrict__ scratch, int tid)
{
    if (tid < 64) {
        const int blk = tid >> 3;
        const int k   = tid & 7;
        const float* p = yrow + blk * 128 + k;
        float r = p[0];
#pragma unroll
        for (int i = 1; i < 16; ++i) r = __fadd_rn(r, p[8 * i]);
        scratch[tid] = r;
    }
    __syncthreads();
    if (tid == 0) {
        float B[8];
#pragma unroll
        for (int blk = 0; blk < 8; ++blk) {
            const float* r = scratch + blk * 8;
            const float s01 = __fadd_rn(r[0], r[1]);
            const float s23 = __fadd_rn(r[2], r[3]);
            const float s45 = __fadd_rn(r[4], r[5]);
            const float s67 = __fadd_rn(r[6], r[7]);
            B[blk] = __fadd_rn(__fadd_rn(s01, s23), __fadd_rn(s45, s67));
        }
        const float c0 = __fadd_rn(B[0], B[1]);
        const float c1 = __fadd_rn(B[2], B[3]);
        const float c2 = __fadd_rn(B[4], B[5]);
        const float c3 = __fadd_rn(B[6], B[7]);
        scratch[64] = __fadd_rn(__fadd_rn(c0, c1), __fadd_rn(c2, c3));
    }
    __syncthreads();
    return scratch[64];
}

__global__ __launch_bounds__(256) void pass_mean_fb(
    const float* __restrict__ x, const float* __restrict__ W,
    float* __restrict__ part)
{
    __shared__ float yrow[1024];
    __shared__ float scratch[65];
    const int tid = threadIdx.x;
    const int o  = blockIdx.x;
    const int tb = blockIdx.y;
    const int m0 = tid * 4;
    float y0, y1, y2, y3;
    e1_row4(x, W, tb >> 4, tb & 15, o, m0, y0, y1, y2, y3);
    *(float4*)&yrow[m0] = make_float4(y0, y1, y2, y3);
    __syncthreads();
    const float P = np_pairwise_1024(yrow, scratch, tid);
    if (tid == 0) part[(size_t)tb * 256 + o] = P;
}

__global__ __launch_bounds__(256) void pass_var_fb(
    const float* __restrict__ x, const float* __restrict__ W,
    const float* __restrict__ mv, float* __restrict__ part)
{
    __shared__ float yrow[1024];
    __shared__ float scratch[65];
    const int tid = threadIdx.x;
    const int o  = blockIdx.x;
    const int tb = blockIdx.y;
    const int m0 = tid * 4;
    const float mean = mv[o];
    float y0, y1, y2, y3;
    e1_row4(x, W, tb >> 4, tb & 15, o, m0, y0, y1, y2, y3);
    const float d0 = __fsub_rn(y0, mean);
    const float d1 = __fsub_rn(y1, mean);
    const float d2 = __fsub_rn(y2, mean);
    const float d3 = __fsub_rn(y3, mean);
    *(float4*)&yrow[m0] = make_float4(__fmul_rn(d0, d0), __fmul_rn(d1, d1),
                                      __fmul_rn(d2, d2), __fmul_rn(d3, d3));
    __syncthreads();
    const float P = np_pairwise_1024(yrow, scratch, tid);
    if (tid == 0) part[(size_t)tb * 256 + o] = P;
}

__global__ __launch_bounds__(256) void pass_lif_fb(
    const float* __restrict__ x, const float* __restrict__ W,
    const float* __restrict__ mv,
    const float* __restrict__ gamma, const float* __restrict__ beta,
    float* __restrict__ out)
{
    const int tid = threadIdx.x;
    const int o = blockIdx.x;
    const int b = blockIdx.y;
    const int m0 = tid * 4;
    const float mean = mv[o];
    const float rs   = mv[256 + o];
    const float g    = gamma[o];
    const float be   = beta[o];
    float v0 = 0.0f, v1 = 0.0f, v2 = 0.0f, v3 = 0.0f;
    for (int t = 0; t < TT; ++t) {
        float y0, y1, y2, y3;
        e1_row4(x, W, t, b, o, m0, y0, y1, y2, y3);
        const float n0 = __fadd_rn(__fmul_rn(__fmul_rn(__fsub_rn(y0, mean), rs), g), be);
        const float n1 = __fadd_rn(__fmul_rn(__fmul_rn(__fsub_rn(y1, mean), rs), g), be);
        const float n2 = __fadd_rn(__fmul_rn(__fmul_rn(__fsub_rn(y2, mean), rs), g), be);
        const float n3 = __fadd_rn(__fmul_rn(__fmul_rn(__fsub_rn(y3, mean), rs), g), be);
        v0 = __fadd_rn(v0, __fmul_rn(__fsub_rn(n0, v0), 0.5f));
        v1 = __fadd_rn(v1, __fmul_rn(__fsub_rn(n1, v1), 0.5f));
        v2 = __fadd_rn(v2, __fmul_rn(__fsub_rn(n2, v2), 0.5f));
        v3 = __fadd_rn(v3, __fmul_rn(__fsub_rn(n3, v3), 0.5f));
        const bool s0 = (v0 >= 1.0f);
        const bool s1 = (v1 >= 1.0f);
        const bool s2 = (v2 >= 1.0f);
        const bool s3 = (v3 >= 1.0f);
        if (s0) v0 = 0.0f;
        if (s1) v1 = 0.0f;
        if (s2) v2 = 0.0f;
        if (s3) v3 = 0.0f;
        const size_t off = ((size_t)(t * BB + b) * CC + o) * MM + m0;
        *(float4*)(out + off) = make_float4(s0 ? 1.0f : 0.0f, s1 ? 1.0f : 0.0f,
                                            s2 ? 1.0f : 0.0f, s3 ? 1.0f : 0.0f);
    }
}

// ---------------------------------------------------------------------------
extern "C" void kernel_launch(void* const* d_in, const int* in_sizes, int n_in,
                              void* d_out, int out_size, void* d_ws, size_t ws_size,
                              hipStream_t stream)
{
    const float* x     = (const float*)d_in[0];
    const float* W     = (const float*)d_in[1];
    const float* gamma = (const float*)d_in[2];
    const float* beta  = (const float*)d_in[3];
    float* out = (float*)d_out;

    const size_t need = ((size_t)NY + 128 * 256 + 512) * sizeof(float);

    if (ws_size >= need) {
        float* y    = (float*)d_ws;
        float* part = y + NY;
        float* mv   = part + 128 * 256;

        einsum_store<<<dim3(2048), dim3(256), 0, stream>>>(x, W, y);
        mean_partial_y<<<dim3(8192), dim3(256), 0, stream>>>(y, part);
        reduce_mean<<<dim3(1), dim3(256), 0, stream>>>(part, mv);
        var_partial_y<<<dim3(8192), dim3(256), 0, stream>>>(y, mv, part);
        reduce_var<<<dim3(1), dim3(256), 0, stream>>>(part, mv);
        lif_from_y<<<dim3(256, 16), dim3(256), 0, stream>>>(y, mv, gamma, beta, out);
    } else {
        float* part = (float*)d_ws;
        float* mv   = part + 128 * 256;
        pass_mean_fb<<<dim3(256, 128), dim3(256), 0, stream>>>(x, W, part);
        reduce_mean<<<dim3(1), dim3(256), 0, stream>>>(part, mv);
        pass_var_fb<<<dim3(256, 128), dim3(256), 0, stream>>>(x, W, mv, part);
        reduce_var<<<dim3(1), dim3(256), 0, stream>>>(part, mv);
        pass_lif_fb<<<dim3(256, 16), dim3(256), 0, stream>>>(x, W, mv, gamma, beta, out);
    }
}